// Round 9
// baseline (128.237 us; speedup 1.0000x reference)
//
#include <hip/hip_runtime.h>
#include <math.h>

// Problem sizes (fixed by reference setup_inputs)
#define BATCH 8
#define NPTS  8192   // pred/full points per batch
#define PPTS  2048   // partial points per batch
#define DLAT  512    // latent dim

typedef __attribute__((ext_vector_type(8))) short short8;   // 8 bf16 (4 VGPR)
typedef __attribute__((ext_vector_type(4))) float floatx4;  // MFMA 16x16 C/D

// Workspace (float elements):
//   [0..4)    acc: sum_pf, sum_fp, sum_fid, sum_kl   (zeroed by minpass blk 0)
//   [4]       uint completion counter                 (zeroed by minpass blk 0)
//   [8..)     ysplit segments of partial min-d^2, each SEG floats
//             (pf | fp | fid regions). Block-owned plain stores, no init.
#define SEG      (2 * BATCH * NPTS + BATCH * PPTS)   // 147456
#define DIR_PF   0
#define DIR_FP   (BATCH * NPTS)
#define DIR_FID  (2 * BATCH * NPTS)
#define OFF_SEG  8

#define CHUNK  1024  // y per LDS stage
#define XBLK   512   // x points per block (4 waves x 8 col-frags of 16)

__device__ __forceinline__ unsigned short f2bf(float f) {  // RNE float->bf16
    unsigned int u = __float_as_uint(f);
    return (unsigned short)((u + 0x7FFFu + ((u >> 16) & 1u)) >> 16);
}
__device__ __forceinline__ float bf2f(unsigned short s) {
    return __uint_as_float(((unsigned int)s) << 16);
}

// K-slot map (K=32; k14..31 zero -- upper half zeroed via lane fragments):
//   k0-2 : yh.xyz * -2xh.xyz      k6-8 : yh.xyz * -2xl.xyz
//   k3-5 : yl.xyz * -2xh.xyz      k9,10: yn_h,yn_l * 1
//   k11-13: yl.xyz * -2xl.xyz  => T = |y|^2 - 2 x.y at ~double-bf16 precision;
//   |x|^2 added post-min in fp32 (monotone hoist).

// Encode one y point into two uint4 k-half records (k0..7 | k8..15).
__device__ __forceinline__ void encodeY(float y0, float y1, float y2,
                                        uint4* r0, uint4* r1) {
    const unsigned short h0 = f2bf(y0), h1 = f2bf(y1), h2 = f2bf(y2);
    const unsigned short l0 = f2bf(y0 - bf2f(h0));
    const unsigned short l1 = f2bf(y1 - bf2f(h1));
    const unsigned short l2 = f2bf(y2 - bf2f(h2));
    const float yn = fmaf(y0, y0, fmaf(y1, y1, y2 * y2));
    const unsigned short nh = f2bf(yn);
    const unsigned short nl = f2bf(yn - bf2f(nh));
    r0->x = (unsigned int)h0 | ((unsigned int)h1 << 16);  // k0,k1
    r0->y = (unsigned int)h2 | ((unsigned int)l0 << 16);  // k2,k3
    r0->z = (unsigned int)l1 | ((unsigned int)l2 << 16);  // k4,k5
    r0->w = (unsigned int)h0 | ((unsigned int)h1 << 16);  // k6,k7
    r1->x = (unsigned int)h2 | ((unsigned int)nh << 16);  // k8,k9
    r1->y = (unsigned int)nl | ((unsigned int)l0 << 16);  // k10,k11
    r1->z = (unsigned int)l1 | ((unsigned int)l2 << 16);  // k12,k13
    r1->w = 0u;                                           // k14,k15
}

// ---------------------------------------------------------------- min pass
// Block = 4 waves; block owns 512 x + 1024-y LDS tile. Wave owns 128 x as
// 8 B-frags of 16 cols; each A-frag read feeds 8 MFMAs. 16x16x32 MFMA keeps
// C/D at 4 regs -> low pressure -> VGPR-form MFMA (no v_accvgpr_read tax,
// which capped R7/R8 at ~43us). Quads 2,3 hold zero B-frags (kills k16..31
// products), so LDS stores only k0..15 (32 B/point).
__global__ __launch_bounds__(256, 3) void minpass_kernel(
        const float* __restrict__ pred,
        const float* __restrict__ full,
        const float* __restrict__ partial,
        float* __restrict__ wsf,
        int ysplit) {
    const int bid = blockIdx.x;          // 8 batches * 36 subs * ysplit
    const int ys  = bid % ysplit;
    const int r   = bid / ysplit;
    const int b   = r / 36;
    const int s   = r % 36;
    const int yhalf = NPTS / ysplit;

    const int t = threadIdx.x;

    // block 0 zeroes acc + counter for the reduce kernel (stream ordering)
    if (bid == 0) {
        if (t < 4) wsf[t] = 0.0f;
        if (t == 4) ((unsigned int*)wsf)[4] = 0u;
    }

    const float* xset; const float* yset; int minoff; int xbase;
    if (s < 16)      { xset = pred;    yset = full; xbase = b*NPTS + s*XBLK;
                       minoff = OFF_SEG + ys*SEG + DIR_PF  + b*NPTS + s*XBLK; }
    else if (s < 32) { xset = full;    yset = pred; xbase = b*NPTS + (s-16)*XBLK;
                       minoff = OFF_SEG + ys*SEG + DIR_FP  + b*NPTS + (s-16)*XBLK; }
    else             { xset = partial; yset = pred; xbase = b*PPTS + (s-32)*XBLK;
                       minoff = OFF_SEG + ys*SEG + DIR_FID + b*PPTS + (s-32)*XBLK; }

    const int lane = t & 63;
    const int wid  = t >> 6;
    const int m    = lane & 15;
    const int quad = lane >> 4;     // 0..3: k-range quad*8..quad*8+7
    const int qh   = quad & 1;      // LDS k-half (mirrored for quads 2,3)

    __shared__ uint4 sY[2][CHUNK];   // y records [k-half][point]  (32 KB)
    __shared__ uint4 sX[2][XBLK];    // x records                  (16 KB)
    __shared__ float sXn[XBLK];      // |x|^2 fp32                 (2 KB)

    // ---- x prep (16B-stride writes per half-array, conflict-free)
    for (int i = t; i < XBLK; i += 256) {
        const float* xp = xset + (size_t)(xbase + i) * 3;
        const float x0 = xp[0], x1 = xp[1], x2 = xp[2];
        const float m0 = -2.0f*x0, m1 = -2.0f*x1, m2 = -2.0f*x2;
        const unsigned short h0 = f2bf(m0), h1 = f2bf(m1), h2 = f2bf(m2);
        const unsigned short l0 = f2bf(m0 - bf2f(h0));
        const unsigned short l1 = f2bf(m1 - bf2f(h1));
        const unsigned short l2 = f2bf(m2 - bf2f(h2));
        const unsigned int one = 0x3F80u;
        uint4 r0, r1;
        r0.x = (unsigned int)h0 | ((unsigned int)h1 << 16);  // k0,k1
        r0.y = (unsigned int)h2 | ((unsigned int)h0 << 16);  // k2,k3
        r0.z = (unsigned int)h1 | ((unsigned int)h2 << 16);  // k4,k5
        r0.w = (unsigned int)l0 | ((unsigned int)l1 << 16);  // k6,k7
        r1.x = (unsigned int)l2 | (one << 16);               // k8,k9
        r1.y = one | ((unsigned int)l0 << 16);               // k10,k11
        r1.z = (unsigned int)l1 | ((unsigned int)l2 << 16);  // k12,k13
        r1.w = 0u;                                           // k14,k15
        sX[0][i] = r0; sX[1][i] = r1;
        sXn[i] = fmaf(x0, x0, fmaf(x1, x1, x2 * x2));
    }
    __syncthreads();

    // B-frags: 8 x-col-groups of 16. Quads 2,3 -> zero (zeroes k16..31).
    const int xw = wid * 128;
    short8 bf[8];
    float  xn[8];
#pragma unroll
    for (int i = 0; i < 8; ++i) {
        short8 v = {0, 0, 0, 0, 0, 0, 0, 0};
        if (quad < 2) v = *(const short8*)&sX[qh][xw + i * 16 + m];
        bf[i] = v;
        xn[i] = sXn[xw + i * 16 + m];
    }

    const floatx4 zc = {0.0f, 0.0f, 0.0f, 0.0f};
    float cmin[8];
#pragma unroll
    for (int i = 0; i < 8; ++i) cmin[i] = 3.4e38f;

    const float* yptsBase = yset + (size_t)(b * NPTS + ys * yhalf) * 3;

    for (int c = 0; c < yhalf; c += CHUNK) {
        __syncthreads();  // protect sY reuse
        // stage 1024 y points (16B-stride writes per half-array)
        for (int i = t; i < CHUNK; i += 256) {
            const float* yp = yptsBase + (size_t)(c + i) * 3;
            uint4 r0, r1;
            encodeY(yp[0], yp[1], yp[2], &r0, &r1);
            sY[0][i] = r0; sY[1][i] = r1;
        }
        __syncthreads();

        // A-frag: quads 2,3 mirror quads 0,1 (harmless: their B is zero).
        short8 af = *(const short8*)&sY[qh][m];
#pragma unroll 4
        for (int j = 0; j < CHUNK / 16; ++j) {
            const short8 afn =
                *(const short8*)&sY[qh][((j + 1) & (CHUNK / 16 - 1)) * 16 + m];
#pragma unroll
            for (int i = 0; i < 8; ++i) {
                const floatx4 d =
                    __builtin_amdgcn_mfma_f32_16x16x32_bf16(af, bf[i], zc, 0, 0, 0);
                const float t3 = fminf(fminf(d[0], d[1]), d[2]);       // v_min3
                cmin[i] = fminf(fminf(d[3], t3), cmin[i]);             // v_min3
            }
            af = afn;
        }
    }

    // epilogue: cross-quad merge (rows quad*4+reg), add |x|^2, store cols
#pragma unroll
    for (int i = 0; i < 8; ++i) {
        float v = cmin[i];
        v = fminf(v, __shfl_xor(v, 16, 64));
        v = fminf(v, __shfl_xor(v, 32, 64));
        if (lane < 16)
            wsf[minoff + xw + i * 16 + m] = fmaxf(v + xn[i], 0.0f);
    }
}

// ---------------------------------------------------------------- reductions
__device__ __forceinline__ float waveReduceSum(float v) {
#pragma unroll
    for (int o = 32; o > 0; o >>= 1) v += __shfl_down(v, o, 64);
    return v;
}

__device__ __forceinline__ float blockReduceSum(float v) {
    __shared__ float wsum[4];
    const int lane = threadIdx.x & 63;
    const int wid  = threadIdx.x >> 6;
    v = waveReduceSum(v);
    if (lane == 0) wsum[wid] = v;
    __syncthreads();
    if (wid == 0) {
        v = (lane < ((int)blockDim.x >> 6)) ? wsum[lane] : 0.0f;
        v = waveReduceSum(v);
    }
    return v;
}

// Blocks 0..63: pf (1024 slots each), 64..127: fp, 128..143: fid, 144: kl.
#define NRED_BLOCKS 145
__global__ __launch_bounds__(256) void reduce_finalize_kernel(
        float* __restrict__ wsf,
        const float* __restrict__ mu,
        const float* __restrict__ logvar,
        float* __restrict__ out,
        int ysplit) {
    float* acc = wsf;
    unsigned int* cnt = (unsigned int*)wsf + 4;
    const int bid = blockIdx.x;
    const int t   = threadIdx.x;

    float v = 0.0f;
    int accIdx;
    if (bid < 144) {
        int base;
        if (bid < 64)       { accIdx = 0; base = DIR_PF  + bid * 1024;         }
        else if (bid < 128) { accIdx = 1; base = DIR_FP  + (bid - 64) * 1024;  }
        else                { accIdx = 2; base = DIR_FID + (bid - 128) * 1024; }
#pragma unroll
        for (int k = 0; k < 4; ++k) {
            const int i = OFF_SEG + base + k * 256 + t;
            float mval = wsf[i];
            for (int sg = 1; sg < ysplit; ++sg)
                mval = fminf(mval, wsf[sg * SEG + i]);
            v += sqrtf(fmaxf(mval, 1e-12f));
        }
    } else {
        accIdx = 3;
#pragma unroll
        for (int k = 0; k < BATCH * DLAT / 256; ++k) {
            const int i = k * 256 + t;
            const float m = mu[i];
            const float l = logvar[i];
            v += -0.5f * (1.0f + l - m * m - expf(l));
        }
    }

    v = blockReduceSum(v);
    if (t == 0) {
        atomicAdd(&acc[accIdx], v);
        __threadfence();
        const unsigned int done = atomicAdd(cnt, 1u);
        if (done == NRED_BLOCKS - 1) {
            const float s_pf  = atomicAdd(&acc[0], 0.0f);
            const float s_fp  = atomicAdd(&acc[1], 0.0f);
            const float s_fid = atomicAdd(&acc[2], 0.0f);
            const float s_kl  = atomicAdd(&acc[3], 0.0f);
            const float cd  = 0.5f * (s_pf / (float)(BATCH * NPTS) +
                                      s_fp / (float)(BATCH * NPTS));
            const float fid = s_fid / (float)(BATCH * PPTS);
            const float kl  = s_kl / (float)BATCH;
            out[0] = cd + 0.01f * kl + 0.5f * fid;  // CD_W=1, BETA=0.01, FID_W=0.5
            out[1] = cd;
            out[2] = kl;
            out[3] = fid;
        }
    }
}

// ---------------------------------------------------------------- launch
extern "C" void kernel_launch(void* const* d_in, const int* in_sizes, int n_in,
                              void* d_out, int out_size, void* d_ws, size_t ws_size,
                              hipStream_t stream) {
    const float* pred    = (const float*)d_in[0];
    const float* full    = (const float*)d_in[1];
    const float* partial = (const float*)d_in[2];
    const float* mu      = (const float*)d_in[3];
    const float* logvar  = (const float*)d_in[4];
    float* out = (float*)d_out;
    float* wsf = (float*)d_ws;

    // ysplit chosen from ws capacity (deterministic: ws_size fixed across calls)
    int ysplit = 2;
    if (ws_size >= (size_t)(OFF_SEG + 8 * SEG) * 4) ysplit = 8;
    else if (ws_size >= (size_t)(OFF_SEG + 4 * SEG) * 4) ysplit = 4;

    // 1. MFMA min-distance pass (block 0 also zeroes acc+counter)
    minpass_kernel<<<8 * 36 * ysplit, 256, 0, stream>>>(pred, full, partial, wsf, ysplit);

    // 2. all reductions + finalize in one dispatch
    reduce_finalize_kernel<<<NRED_BLOCKS, 256, 0, stream>>>(wsf, mu, logvar, out, ysplit);
}

// Round 10
// 110.502 us; speedup vs baseline: 1.1605x; 1.1605x over previous
//
#include <hip/hip_runtime.h>
#include <math.h>

// Problem sizes (fixed by reference setup_inputs)
#define BATCH 8
#define NPTS  8192   // pred/full points per batch
#define PPTS  2048   // partial points per batch
#define DLAT  512    // latent dim

typedef __attribute__((ext_vector_type(8)))  short short8;    // 8 bf16 (4 VGPR)
typedef __attribute__((ext_vector_type(16))) float floatx16;  // MFMA 32x32 C/D

// Workspace (float elements):
//   [0..4)    acc: sum_pf, sum_fp, sum_fid, sum_kl   (zeroed by minpass blk 0)
//   [4]       uint completion counter                 (zeroed by minpass blk 0)
//   [8..)     ysplit segments of partial min-d^2, each SEG floats
//             (pf | fp | fid regions). Block-owned plain stores, no init.
#define SEG      (2 * BATCH * NPTS + BATCH * PPTS)   // 147456
#define DIR_PF   0
#define DIR_FP   (BATCH * NPTS)
#define DIR_FID  (2 * BATCH * NPTS)
#define OFF_SEG  8

#define CHUNK  512   // y per LDS stage (34 KB total LDS -> 4 blocks/CU)
#define XBLK   512   // x points per block (4 waves x 4 col-groups of 32)

__device__ __forceinline__ unsigned short f2bf(float f) {  // RNE float->bf16
    unsigned int u = __float_as_uint(f);
    return (unsigned short)((u + 0x7FFFu + ((u >> 16) & 1u)) >> 16);
}
__device__ __forceinline__ float bf2f(unsigned short s) {
    return __uint_as_float(((unsigned int)s) << 16);
}

// MFMA via inline asm with "=v" (arch-VGPR) destination: the compiler's
// builtin path allocates C/D in AGPRs and pays 16 v_accvgpr_read per MFMA
// before the min tree (R7-R9: VALU 2.5x the min-tree floor). The "v"
// constraint forces a VGPR tuple, so fminf reads results directly.
__device__ __forceinline__ floatx16 mfma_v(short8 a, short8 b, floatx16 c) {
    floatx16 d;
    asm("v_mfma_f32_32x32x16_bf16 %0, %1, %2, %3"
        : "=v"(d) : "v"(a), "v"(b), "v"(c));
    return d;
}

// min over 16 accumulator regs (16 rows of this lane's column) + carry-in.
// 8 v_min3_f32 + 1 v_min = optimal ternary tree.
__device__ __forceinline__ float min16(floatx16 d, float prev) {
    float a0 = fminf(fminf(d[0],  d[1]),  d[2]);
    float a1 = fminf(fminf(d[3],  d[4]),  d[5]);
    float a2 = fminf(fminf(d[6],  d[7]),  d[8]);
    float a3 = fminf(fminf(d[9],  d[10]), d[11]);
    float a4 = fminf(fminf(d[12], d[13]), d[14]);
    float b0 = fminf(fminf(a0, a1), a2);
    float b1 = fminf(fminf(a3, a4), d[15]);
    return fminf(fminf(b0, b1), prev);
}

// Encode one y point + its norm into two uint4 k-half records.
__device__ __forceinline__ void encodeY(float y0, float y1, float y2,
                                        uint4* r0, uint4* r1) {
    const unsigned short h0 = f2bf(y0), h1 = f2bf(y1), h2 = f2bf(y2);
    const unsigned short l0 = f2bf(y0 - bf2f(h0));
    const unsigned short l1 = f2bf(y1 - bf2f(h1));
    const unsigned short l2 = f2bf(y2 - bf2f(h2));
    const float yn = fmaf(y0, y0, fmaf(y1, y1, y2 * y2));
    const unsigned short nh = f2bf(yn);
    const unsigned short nl = f2bf(yn - bf2f(nh));
    r0->x = (unsigned int)h0 | ((unsigned int)h1 << 16);  // k0,k1: yh.x,yh.y
    r0->y = (unsigned int)h2 | ((unsigned int)l0 << 16);  // k2,k3: yh.z,yl.x
    r0->z = (unsigned int)l1 | ((unsigned int)l2 << 16);  // k4,k5: yl.y,yl.z
    r0->w = (unsigned int)h0 | ((unsigned int)h1 << 16);  // k6,k7: yh.x,yh.y
    r1->x = (unsigned int)h2 | ((unsigned int)nh << 16);  // k8,k9: yh.z,yn_h
    r1->y = (unsigned int)nl;                             // k10, k11=0
    r1->z = 0u; r1->w = 0u;
}

// ---------------------------------------------------------------- min pass
// K-slot scheme (11 of 16 used):
//   A(y): k0-2 yh | k3-5 yl | k6-8 yh | k9 yn_h | k10 yn_l | rest 0
//   B(x): k0-2 -2xh | k3-5 -2xh | k6-8 -2xl | k9 1 | k10 1 | rest 0
//   => T = |y|^2 - 2 x.y (split residual ~1e-4); |x|^2 added post-min in fp32.
// Block = 4 waves; block owns 512 x; wave owns 128 x (4 col-groups of 32)
// so each staged A-fragment feeds 4 MFMAs (32x32x16: 1024 pairs/inst — the
// best pair-throughput shape; 16x16x32 was 2x worse, R9 regression).
__global__ __launch_bounds__(256, 3) void minpass_kernel(
        const float* __restrict__ pred,
        const float* __restrict__ full,
        const float* __restrict__ partial,
        float* __restrict__ wsf,
        int ysplit) {
    const int bid = blockIdx.x;          // 8 batches * 36 subs * ysplit
    const int ys  = bid % ysplit;
    const int r   = bid / ysplit;
    const int b   = r / 36;
    const int s   = r % 36;
    const int yhalf = NPTS / ysplit;

    const int t = threadIdx.x;

    // block 0 zeroes acc + counter for the reduce kernel (stream ordering)
    if (bid == 0) {
        if (t < 4) wsf[t] = 0.0f;
        if (t == 4) ((unsigned int*)wsf)[4] = 0u;
    }

    const float* xset; const float* yset; int minoff; int xbase;
    if (s < 16)      { xset = pred;    yset = full; xbase = b*NPTS + s*XBLK;
                       minoff = OFF_SEG + ys*SEG + DIR_PF  + b*NPTS + s*XBLK; }
    else if (s < 32) { xset = full;    yset = pred; xbase = b*NPTS + (s-16)*XBLK;
                       minoff = OFF_SEG + ys*SEG + DIR_FP  + b*NPTS + (s-16)*XBLK; }
    else             { xset = partial; yset = pred; xbase = b*PPTS + (s-32)*XBLK;
                       minoff = OFF_SEG + ys*SEG + DIR_FID + b*PPTS + (s-32)*XBLK; }

    const int lane = t & 63;
    const int wid  = t >> 6;
    const int l31  = lane & 31;
    const int half = lane >> 5;

    __shared__ uint4 sY[2][CHUNK];   // y records [k-half][point]  (16 KB)
    __shared__ uint4 sX[2][XBLK];    // x records                  (16 KB)
    __shared__ float sXn[XBLK];      // |x|^2 fp32                 (2 KB)

    // ---- x prep (16B-stride writes, conflict-free)
    for (int i = t; i < XBLK; i += 256) {
        const float* xp = xset + (size_t)(xbase + i) * 3;
        const float x0 = xp[0], x1 = xp[1], x2 = xp[2];
        const float m0 = -2.0f*x0, m1 = -2.0f*x1, m2 = -2.0f*x2;
        const unsigned short h0 = f2bf(m0), h1 = f2bf(m1), h2 = f2bf(m2);
        const unsigned short l0 = f2bf(m0 - bf2f(h0));
        const unsigned short l1 = f2bf(m1 - bf2f(h1));
        const unsigned short l2 = f2bf(m2 - bf2f(h2));
        const unsigned int one = 0x3F80u;
        uint4 r0, r1;
        r0.x = (unsigned int)h0 | ((unsigned int)h1 << 16);  // k0,k1
        r0.y = (unsigned int)h2 | ((unsigned int)h0 << 16);  // k2,k3
        r0.z = (unsigned int)h1 | ((unsigned int)h2 << 16);  // k4,k5
        r0.w = (unsigned int)l0 | ((unsigned int)l1 << 16);  // k6,k7
        r1.x = (unsigned int)l2 | (one << 16);               // k8,k9
        r1.y = one;                                          // k10,k11=0
        r1.z = 0u; r1.w = 0u;
        sX[0][i] = r0; sX[1][i] = r1;
        sXn[i] = fmaf(x0, x0, fmaf(x1, x1, x2 * x2));
    }
    __syncthreads();

    const int xw = wid * 128;
    const short8 bf0 = *(const short8*)&sX[half][xw + l31];
    const short8 bf1 = *(const short8*)&sX[half][xw + 32 + l31];
    const short8 bf2 = *(const short8*)&sX[half][xw + 64 + l31];
    const short8 bf3 = *(const short8*)&sX[half][xw + 96 + l31];
    const float  xn0 = sXn[xw + l31];
    const float  xn1 = sXn[xw + 32 + l31];
    const float  xn2 = sXn[xw + 64 + l31];
    const float  xn3 = sXn[xw + 96 + l31];

    const floatx16 zc = {0,0,0,0, 0,0,0,0, 0,0,0,0, 0,0,0,0};
    float cmin0 = 3.4e38f, cmin1 = 3.4e38f, cmin2 = 3.4e38f, cmin3 = 3.4e38f;

    const float* yptsBase = yset + (size_t)(b * NPTS + ys * yhalf) * 3;

    for (int c = 0; c < yhalf; c += CHUNK) {
        __syncthreads();  // protect sY reuse
        // stage 512 y points (16B-stride writes, conflict-free)
        for (int i = t; i < CHUNK; i += 256) {
            const float* yp = yptsBase + (size_t)(c + i) * 3;
            uint4 r0, r1;
            encodeY(yp[0], yp[1], yp[2], &r0, &r1);
            sY[0][i] = r0; sY[1][i] = r1;
        }
        __syncthreads();

        const uint4* sYh = &sY[half][0];
        short8 af = *(const short8*)&sYh[l31];
#pragma unroll 4
        for (int j = 0; j < CHUNK / 32; ++j) {
            const short8 afn =
                *(const short8*)&sYh[((j + 1) & (CHUNK/32 - 1)) * 32 + l31];
            // staggered: 4 independent MFMA->min chains for ILP
            const floatx16 d0 = mfma_v(af, bf0, zc);
            const floatx16 d1 = mfma_v(af, bf1, zc);
            cmin0 = min16(d0, cmin0);
            const floatx16 d2 = mfma_v(af, bf2, zc);
            cmin1 = min16(d1, cmin1);
            const floatx16 d3 = mfma_v(af, bf3, zc);
            cmin2 = min16(d2, cmin2);
            cmin3 = min16(d3, cmin3);
            af = afn;
        }
    }

    // merge the two lane-halves (same column, different row halves), add |x|^2
    const float m0 = fminf(cmin0, __shfl_xor(cmin0, 32, 64));
    const float m1 = fminf(cmin1, __shfl_xor(cmin1, 32, 64));
    const float m2 = fminf(cmin2, __shfl_xor(cmin2, 32, 64));
    const float m3 = fminf(cmin3, __shfl_xor(cmin3, 32, 64));
    if (lane < 32) {
        wsf[minoff + xw + l31]      = fmaxf(m0 + xn0, 0.0f);
        wsf[minoff + xw + 32 + l31] = fmaxf(m1 + xn1, 0.0f);
        wsf[minoff + xw + 64 + l31] = fmaxf(m2 + xn2, 0.0f);
        wsf[minoff + xw + 96 + l31] = fmaxf(m3 + xn3, 0.0f);
    }
}

// ---------------------------------------------------------------- reductions
__device__ __forceinline__ float waveReduceSum(float v) {
#pragma unroll
    for (int o = 32; o > 0; o >>= 1) v += __shfl_down(v, o, 64);
    return v;
}

__device__ __forceinline__ float blockReduceSum(float v) {
    __shared__ float wsum[4];
    const int lane = threadIdx.x & 63;
    const int wid  = threadIdx.x >> 6;
    v = waveReduceSum(v);
    if (lane == 0) wsum[wid] = v;
    __syncthreads();
    if (wid == 0) {
        v = (lane < ((int)blockDim.x >> 6)) ? wsum[lane] : 0.0f;
        v = waveReduceSum(v);
    }
    return v;
}

// Blocks 0..63: pf (1024 slots each), 64..127: fp, 128..143: fid, 144: kl.
#define NRED_BLOCKS 145
__global__ __launch_bounds__(256) void reduce_finalize_kernel(
        float* __restrict__ wsf,
        const float* __restrict__ mu,
        const float* __restrict__ logvar,
        float* __restrict__ out,
        int ysplit) {
    float* acc = wsf;
    unsigned int* cnt = (unsigned int*)wsf + 4;
    const int bid = blockIdx.x;
    const int t   = threadIdx.x;

    float v = 0.0f;
    int accIdx;
    if (bid < 144) {
        int base;
        if (bid < 64)       { accIdx = 0; base = DIR_PF  + bid * 1024;         }
        else if (bid < 128) { accIdx = 1; base = DIR_FP  + (bid - 64) * 1024;  }
        else                { accIdx = 2; base = DIR_FID + (bid - 128) * 1024; }
#pragma unroll
        for (int k = 0; k < 4; ++k) {
            const int i = OFF_SEG + base + k * 256 + t;
            float mval = wsf[i];
            for (int sg = 1; sg < ysplit; ++sg)
                mval = fminf(mval, wsf[sg * SEG + i]);
            v += sqrtf(fmaxf(mval, 1e-12f));
        }
    } else {
        accIdx = 3;
#pragma unroll
        for (int k = 0; k < BATCH * DLAT / 256; ++k) {
            const int i = k * 256 + t;
            const float m = mu[i];
            const float l = logvar[i];
            v += -0.5f * (1.0f + l - m * m - expf(l));
        }
    }

    v = blockReduceSum(v);
    if (t == 0) {
        atomicAdd(&acc[accIdx], v);
        __threadfence();
        const unsigned int done = atomicAdd(cnt, 1u);
        if (done == NRED_BLOCKS - 1) {
            const float s_pf  = atomicAdd(&acc[0], 0.0f);
            const float s_fp  = atomicAdd(&acc[1], 0.0f);
            const float s_fid = atomicAdd(&acc[2], 0.0f);
            const float s_kl  = atomicAdd(&acc[3], 0.0f);
            const float cd  = 0.5f * (s_pf / (float)(BATCH * NPTS) +
                                      s_fp / (float)(BATCH * NPTS));
            const float fid = s_fid / (float)(BATCH * PPTS);
            const float kl  = s_kl / (float)BATCH;
            out[0] = cd + 0.01f * kl + 0.5f * fid;  // CD_W=1, BETA=0.01, FID_W=0.5
            out[1] = cd;
            out[2] = kl;
            out[3] = fid;
        }
    }
}

// ---------------------------------------------------------------- launch
extern "C" void kernel_launch(void* const* d_in, const int* in_sizes, int n_in,
                              void* d_out, int out_size, void* d_ws, size_t ws_size,
                              hipStream_t stream) {
    const float* pred    = (const float*)d_in[0];
    const float* full    = (const float*)d_in[1];
    const float* partial = (const float*)d_in[2];
    const float* mu      = (const float*)d_in[3];
    const float* logvar  = (const float*)d_in[4];
    float* out = (float*)d_out;
    float* wsf = (float*)d_ws;

    // ysplit chosen from ws capacity (deterministic: ws_size fixed across calls)
    int ysplit = 2;
    if (ws_size >= (size_t)(OFF_SEG + 8 * SEG) * 4) ysplit = 8;
    else if (ws_size >= (size_t)(OFF_SEG + 4 * SEG) * 4) ysplit = 4;

    // 1. MFMA min-distance pass (block 0 also zeroes acc+counter)
    minpass_kernel<<<8 * 36 * ysplit, 256, 0, stream>>>(pred, full, partial, wsf, ysplit);

    // 2. all reductions + finalize in one dispatch
    reduce_finalize_kernel<<<NRED_BLOCKS, 256, 0, stream>>>(wsf, mu, logvar, out, ysplit);
}

// Round 11
// 109.096 us; speedup vs baseline: 1.1754x; 1.0129x over previous
//
#include <hip/hip_runtime.h>
#include <math.h>

// Problem sizes (fixed by reference setup_inputs)
#define BATCH 8
#define NPTS  8192   // pred/full points per batch
#define PPTS  2048   // partial points per batch
#define DLAT  512    // latent dim

typedef __attribute__((ext_vector_type(8)))  short short8;    // 8 bf16 (4 VGPR)
typedef __attribute__((ext_vector_type(16))) float floatx16;  // MFMA 32x32 C/D

// Workspace (float elements):
//   [0..4)    acc: sum_pf, sum_fp, sum_fid, sum_kl   (zeroed by minpass blk 0)
//   [4]       uint completion counter                 (zeroed by minpass blk 0)
//   [8..)     ysplit segments of partial min-d^2, each SEG floats
//             (pf | fp | fid regions). Block-owned plain stores, no init.
#define SEG      (2 * BATCH * NPTS + BATCH * PPTS)   // 147456
#define DIR_PF   0
#define DIR_FP   (BATCH * NPTS)
#define DIR_FID  (2 * BATCH * NPTS)
#define OFF_SEG  8

#define CHUNK  512   // y per LDS stage (16 KB total LDS -> LDS cap 10 blk/CU)
#define XBLK   512   // x points per block (4 waves x 4 col-groups of 32)

__device__ __forceinline__ unsigned short f2bf(float f) {  // RNE float->bf16
    unsigned int u = __float_as_uint(f);
    return (unsigned short)((u + 0x7FFFu + ((u >> 16) & 1u)) >> 16);
}
__device__ __forceinline__ float bf2f(unsigned short s) {
    return __uint_as_float(((unsigned int)s) << 16);
}

// MFMA via inline asm with "=v" (arch-VGPR) destination so min trees read
// results directly (no v_accvgpr_read round-trip).
__device__ __forceinline__ floatx16 mfma_v(short8 a, short8 b, floatx16 c) {
    floatx16 d;
    asm("v_mfma_f32_32x32x16_bf16 %0, %1, %2, %3"
        : "=v"(d) : "v"(a), "v"(b), "v"(c));
    return d;
}

// min over 16 accumulator regs (16 rows of this lane's column) + carry-in.
__device__ __forceinline__ float min16(floatx16 d, float prev) {
    float a0 = fminf(fminf(d[0],  d[1]),  d[2]);
    float a1 = fminf(fminf(d[3],  d[4]),  d[5]);
    float a2 = fminf(fminf(d[6],  d[7]),  d[8]);
    float a3 = fminf(fminf(d[9],  d[10]), d[11]);
    float a4 = fminf(fminf(d[12], d[13]), d[14]);
    float b0 = fminf(fminf(a0, a1), a2);
    float b1 = fminf(fminf(a3, a4), d[15]);
    return fminf(fminf(b0, b1), prev);
}

// Encode one y point + its norm into two uint4 k-half records.
// A(y): k0-2 yh | k3-5 yl | k6-8 yh | k9 yn_h | k10 yn_l | k11-15 0
__device__ __forceinline__ void encodeY(float y0, float y1, float y2,
                                        uint4* r0, uint4* r1) {
    const unsigned short h0 = f2bf(y0), h1 = f2bf(y1), h2 = f2bf(y2);
    const unsigned short l0 = f2bf(y0 - bf2f(h0));
    const unsigned short l1 = f2bf(y1 - bf2f(h1));
    const unsigned short l2 = f2bf(y2 - bf2f(h2));
    const float yn = fmaf(y0, y0, fmaf(y1, y1, y2 * y2));
    const unsigned short nh = f2bf(yn);
    const unsigned short nl = f2bf(yn - bf2f(nh));
    r0->x = (unsigned int)h0 | ((unsigned int)h1 << 16);  // k0,k1
    r0->y = (unsigned int)h2 | ((unsigned int)l0 << 16);  // k2,k3
    r0->z = (unsigned int)l1 | ((unsigned int)l2 << 16);  // k4,k5
    r0->w = (unsigned int)h0 | ((unsigned int)h1 << 16);  // k6,k7
    r1->x = (unsigned int)h2 | ((unsigned int)nh << 16);  // k8,k9
    r1->y = (unsigned int)nl;                             // k10, k11=0
    r1->z = 0u; r1->w = 0u;
}

// Per-lane B-fragment: encode -2x for this lane's k-half, no LDS round-trip.
// B(x): k0-2 -2xh | k3-5 -2xh | k6-8 -2xl | k9 1 | k10 1 | k11-15 0
__device__ __forceinline__ short8 encodeX(float x0, float x1, float x2,
                                          int half) {
    const float m0 = -2.0f * x0, m1 = -2.0f * x1, m2 = -2.0f * x2;
    const unsigned short h0 = f2bf(m0), h1 = f2bf(m1), h2 = f2bf(m2);
    const unsigned short l0 = f2bf(m0 - bf2f(h0));
    const unsigned short l1 = f2bf(m1 - bf2f(h1));
    const unsigned short l2 = f2bf(m2 - bf2f(h2));
    const unsigned short one = 0x3F80u;
    union { unsigned short u[8]; short8 v; } r;
    if (half == 0) {
        r.u[0] = h0; r.u[1] = h1; r.u[2] = h2; r.u[3] = h0;
        r.u[4] = h1; r.u[5] = h2; r.u[6] = l0; r.u[7] = l1;
    } else {
        r.u[0] = l2; r.u[1] = one; r.u[2] = one; r.u[3] = 0;
        r.u[4] = 0;  r.u[5] = 0;   r.u[6] = 0;   r.u[7] = 0;
    }
    return r.v;
}

// ---------------------------------------------------------------- min pass
// T = |y|^2 - 2 x.y (split bf16, residual ~1e-4); |x|^2 added post-min fp32.
// Block = 4 waves; block owns 512 x; wave owns 128 x (4 col-groups of 32).
// LDS holds ONLY the y tile (16 KB) — B-frags are built per-lane from global
// (x tile 6 KB, L1/L2 resident) to double resident blocks/CU vs R10.
__global__ __launch_bounds__(256, 4) void minpass_kernel(
        const float* __restrict__ pred,
        const float* __restrict__ full,
        const float* __restrict__ partial,
        float* __restrict__ wsf,
        int ysplit) {
    const int bid = blockIdx.x;          // 8 batches * 36 subs * ysplit
    const int ys  = bid % ysplit;
    const int r   = bid / ysplit;
    const int b   = r / 36;
    const int s   = r % 36;
    const int yhalf = NPTS / ysplit;

    const int t = threadIdx.x;

    // block 0 zeroes acc + counter for the reduce kernel (stream ordering)
    if (bid == 0) {
        if (t < 4) wsf[t] = 0.0f;
        if (t == 4) ((unsigned int*)wsf)[4] = 0u;
    }

    const float* xset; const float* yset; int minoff; int xbase;
    if (s < 16)      { xset = pred;    yset = full; xbase = b*NPTS + s*XBLK;
                       minoff = OFF_SEG + ys*SEG + DIR_PF  + b*NPTS + s*XBLK; }
    else if (s < 32) { xset = full;    yset = pred; xbase = b*NPTS + (s-16)*XBLK;
                       minoff = OFF_SEG + ys*SEG + DIR_FP  + b*NPTS + (s-16)*XBLK; }
    else             { xset = partial; yset = pred; xbase = b*PPTS + (s-32)*XBLK;
                       minoff = OFF_SEG + ys*SEG + DIR_FID + b*PPTS + (s-32)*XBLK; }

    const int lane = t & 63;
    const int wid  = t >> 6;
    const int l31  = lane & 31;
    const int half = lane >> 5;

    __shared__ uint4 sY[2][CHUNK];   // y records [k-half][point]  (16 KB)

    // ---- per-lane B-frags + |x|^2 (no LDS, no barrier)
    const int xw = wid * 128;
    short8 bf0, bf1, bf2, bf3;
    float xn0, xn1, xn2, xn3;
    {
        const float* xp0 = xset + (size_t)(xbase + xw + l31) * 3;
        const float* xp1 = xset + (size_t)(xbase + xw + 32 + l31) * 3;
        const float* xp2 = xset + (size_t)(xbase + xw + 64 + l31) * 3;
        const float* xp3 = xset + (size_t)(xbase + xw + 96 + l31) * 3;
        const float a0 = xp0[0], a1 = xp0[1], a2 = xp0[2];
        const float b0 = xp1[0], b1 = xp1[1], b2 = xp1[2];
        const float c0 = xp2[0], c1 = xp2[1], c2 = xp2[2];
        const float e0 = xp3[0], e1 = xp3[1], e2 = xp3[2];
        bf0 = encodeX(a0, a1, a2, half);
        bf1 = encodeX(b0, b1, b2, half);
        bf2 = encodeX(c0, c1, c2, half);
        bf3 = encodeX(e0, e1, e2, half);
        xn0 = fmaf(a0, a0, fmaf(a1, a1, a2 * a2));
        xn1 = fmaf(b0, b0, fmaf(b1, b1, b2 * b2));
        xn2 = fmaf(c0, c0, fmaf(c1, c1, c2 * c2));
        xn3 = fmaf(e0, e0, fmaf(e1, e1, e2 * e2));
    }

    const floatx16 zc = {0,0,0,0, 0,0,0,0, 0,0,0,0, 0,0,0,0};
    float cmin0 = 3.4e38f, cmin1 = 3.4e38f, cmin2 = 3.4e38f, cmin3 = 3.4e38f;

    const float* yptsBase = yset + (size_t)(b * NPTS + ys * yhalf) * 3;

    for (int c = 0; c < yhalf; c += CHUNK) {
        __syncthreads();  // protect sY reuse
        // stage 512 y points (16B-stride writes, conflict-free)
        for (int i = t; i < CHUNK; i += 256) {
            const float* yp = yptsBase + (size_t)(c + i) * 3;
            uint4 r0, r1;
            encodeY(yp[0], yp[1], yp[2], &r0, &r1);
            sY[0][i] = r0; sY[1][i] = r1;
        }
        __syncthreads();

        const uint4* sYh = &sY[half][0];
        short8 af = *(const short8*)&sYh[l31];
#pragma unroll 4
        for (int j = 0; j < CHUNK / 32; ++j) {
            const short8 afn =
                *(const short8*)&sYh[((j + 1) & (CHUNK/32 - 1)) * 32 + l31];
            // staggered: 4 independent MFMA->min chains for ILP
            const floatx16 d0 = mfma_v(af, bf0, zc);
            const floatx16 d1 = mfma_v(af, bf1, zc);
            cmin0 = min16(d0, cmin0);
            const floatx16 d2 = mfma_v(af, bf2, zc);
            cmin1 = min16(d1, cmin1);
            const floatx16 d3 = mfma_v(af, bf3, zc);
            cmin2 = min16(d2, cmin2);
            cmin3 = min16(d3, cmin3);
            af = afn;
        }
    }

    // merge the two lane-halves (same column, different row halves), add |x|^2
    const float m0 = fminf(cmin0, __shfl_xor(cmin0, 32, 64));
    const float m1 = fminf(cmin1, __shfl_xor(cmin1, 32, 64));
    const float m2 = fminf(cmin2, __shfl_xor(cmin2, 32, 64));
    const float m3 = fminf(cmin3, __shfl_xor(cmin3, 32, 64));
    if (lane < 32) {
        wsf[minoff + xw + l31]      = fmaxf(m0 + xn0, 0.0f);
        wsf[minoff + xw + 32 + l31] = fmaxf(m1 + xn1, 0.0f);
        wsf[minoff + xw + 64 + l31] = fmaxf(m2 + xn2, 0.0f);
        wsf[minoff + xw + 96 + l31] = fmaxf(m3 + xn3, 0.0f);
    }
}

// ---------------------------------------------------------------- reductions
__device__ __forceinline__ float waveReduceSum(float v) {
#pragma unroll
    for (int o = 32; o > 0; o >>= 1) v += __shfl_down(v, o, 64);
    return v;
}

__device__ __forceinline__ float blockReduceSum(float v) {
    __shared__ float wsum[4];
    const int lane = threadIdx.x & 63;
    const int wid  = threadIdx.x >> 6;
    v = waveReduceSum(v);
    if (lane == 0) wsum[wid] = v;
    __syncthreads();
    if (wid == 0) {
        v = (lane < ((int)blockDim.x >> 6)) ? wsum[lane] : 0.0f;
        v = waveReduceSum(v);
    }
    return v;
}

// Blocks 0..63: pf (1024 slots each), 64..127: fp, 128..143: fid, 144: kl.
#define NRED_BLOCKS 145
__global__ __launch_bounds__(256) void reduce_finalize_kernel(
        float* __restrict__ wsf,
        const float* __restrict__ mu,
        const float* __restrict__ logvar,
        float* __restrict__ out,
        int ysplit) {
    float* acc = wsf;
    unsigned int* cnt = (unsigned int*)wsf + 4;
    const int bid = blockIdx.x;
    const int t   = threadIdx.x;

    float v = 0.0f;
    int accIdx;
    if (bid < 144) {
        int base;
        if (bid < 64)       { accIdx = 0; base = DIR_PF  + bid * 1024;         }
        else if (bid < 128) { accIdx = 1; base = DIR_FP  + (bid - 64) * 1024;  }
        else                { accIdx = 2; base = DIR_FID + (bid - 128) * 1024; }
#pragma unroll
        for (int k = 0; k < 4; ++k) {
            const int i = OFF_SEG + base + k * 256 + t;
            float mval = wsf[i];
            for (int sg = 1; sg < ysplit; ++sg)
                mval = fminf(mval, wsf[sg * SEG + i]);
            v += sqrtf(fmaxf(mval, 1e-12f));
        }
    } else {
        accIdx = 3;
#pragma unroll
        for (int k = 0; k < BATCH * DLAT / 256; ++k) {
            const int i = k * 256 + t;
            const float m = mu[i];
            const float l = logvar[i];
            v += -0.5f * (1.0f + l - m * m - expf(l));
        }
    }

    v = blockReduceSum(v);
    if (t == 0) {
        atomicAdd(&acc[accIdx], v);
        __threadfence();
        const unsigned int done = atomicAdd(cnt, 1u);
        if (done == NRED_BLOCKS - 1) {
            const float s_pf  = atomicAdd(&acc[0], 0.0f);
            const float s_fp  = atomicAdd(&acc[1], 0.0f);
            const float s_fid = atomicAdd(&acc[2], 0.0f);
            const float s_kl  = atomicAdd(&acc[3], 0.0f);
            const float cd  = 0.5f * (s_pf / (float)(BATCH * NPTS) +
                                      s_fp / (float)(BATCH * NPTS));
            const float fid = s_fid / (float)(BATCH * PPTS);
            const float kl  = s_kl / (float)BATCH;
            out[0] = cd + 0.01f * kl + 0.5f * fid;  // CD_W=1, BETA=0.01, FID_W=0.5
            out[1] = cd;
            out[2] = kl;
            out[3] = fid;
        }
    }
}

// ---------------------------------------------------------------- launch
extern "C" void kernel_launch(void* const* d_in, const int* in_sizes, int n_in,
                              void* d_out, int out_size, void* d_ws, size_t ws_size,
                              hipStream_t stream) {
    const float* pred    = (const float*)d_in[0];
    const float* full    = (const float*)d_in[1];
    const float* partial = (const float*)d_in[2];
    const float* mu      = (const float*)d_in[3];
    const float* logvar  = (const float*)d_in[4];
    float* out = (float*)d_out;
    float* wsf = (float*)d_ws;

    // ysplit chosen from ws capacity (deterministic: ws_size fixed across calls)
    int ysplit = 2;
    if (ws_size >= (size_t)(OFF_SEG + 8 * SEG) * 4) ysplit = 8;
    else if (ws_size >= (size_t)(OFF_SEG + 4 * SEG) * 4) ysplit = 4;

    // 1. MFMA min-distance pass (block 0 also zeroes acc+counter)
    minpass_kernel<<<8 * 36 * ysplit, 256, 0, stream>>>(pred, full, partial, wsf, ysplit);

    // 2. all reductions + finalize in one dispatch
    reduce_finalize_kernel<<<NRED_BLOCKS, 256, 0, stream>>>(wsf, mu, logvar, out, ysplit);
}